// Round 6
// baseline (780.684 us; speedup 1.0000x reference)
//
#include <hip/hip_runtime.h>

#define N_NODES 50000
#define N_EDGES 800000
#define IN_C    512
#define HID_C   256
#define OUT_C   40
#define BN_EPS  1e-5f
#define ELL_CAP 64
#define GT64    782      // ceil(N_NODES/64)
#define EB      3125     // N_EDGES/256
#define PB      12500    // N_NODES/4
#define CVTB    15625    // N_NODES*80/256

typedef _Float16 half2v __attribute__((ext_vector_type(2)));
typedef _Float16 half4v __attribute__((ext_vector_type(4)));
typedef _Float16 half8  __attribute__((ext_vector_type(8)));
typedef float    f32x16 __attribute__((ext_vector_type(16)));
typedef unsigned long long ull;

// ---------------- static device buffers ----------------
__device__ _Float16 g_h16 [(size_t)N_NODES * HID_C]; // BN+ReLU'd hidden (fp16)
__device__ _Float16 g_Ah  [(size_t)N_NODES * HID_C]; // gemm out (fp16)
__device__ _Float16 g_P   [(size_t)N_NODES * HID_C]; // prop out (fp16, pre-BN)
__device__ _Float16 g_o40h[(size_t)N_NODES * OUT_C]; // out-layer gemm (fp16)
__device__ _Float16 g_l80a[(size_t)N_NODES * 80];    // labels interleaved y1|y2 fp16
__device__ _Float16 g_l80b[(size_t)N_NODES * 80];
__device__ _Float16 g_w0t[HID_C * IN_C];             // W0^T blocked+swizzled [K/32][256][32]
__device__ _Float16 g_w1t[HID_C * HID_C];            // W1^T blocked+swizzled
__device__ _Float16 g_w2t[64 * HID_C];               // W2^T swizzled [64][256]
__device__ int2  g_ell[(size_t)N_NODES * ELL_CAP];   // padded edge slots {col, raw w bits}
__device__ int   g_fill[N_NODES];                    // per-row fill count (= degree)
__device__ float g_dinv[N_NODES];
__device__ float g_bnstat[4 * HID_C];                // sum0|ss0|sum1|ss1
__device__ float g_bnss  [4 * HID_C];                // scale0|shift0|scale1|shift1

// ---------------- device bodies (indexing via explicit bid) ----------------
__device__ __forceinline__ void fill_body(const int* __restrict__ row,
                                          const int* __restrict__ col,
                                          const float* __restrict__ w, int bid) {
    int e = bid * 256 + threadIdx.x;
    if (e < N_EDGES) {
        int r = row[e];
        int pos = atomicAdd(&g_fill[r], 1);
        if (pos < ELL_CAP)    // deg ~ Poisson(16): never triggers; guards OOB
            g_ell[(size_t)r * ELL_CAP + pos] = make_int2(col[e], __float_as_int(w[e]));
    }
}

__device__ __forceinline__ void cvt_body(const float* __restrict__ lab1,
                                         const float* __restrict__ lab2,
                                         _Float16* __restrict__ out, int bid) {
    int idx = bid * 256 + threadIdx.x;
    if (idx >= N_NODES * 80) return;
    int i = idx / 80, cc = idx - 80 * i;
    float v = (cc < OUT_C) ? lab1[(size_t)i * OUT_C + cc]
                           : lab2[(size_t)i * OUT_C + cc - OUT_C];
    out[idx] = (_Float16)v;
}

__device__ __forceinline__ half8 load_a8(const _Float16* p) { return *(const half8*)p; }
__device__ __forceinline__ half8 load_a8(const float* p) {
    float4 a0 = *(const float4*)p;
    float4 a1 = *(const float4*)(p + 4);
    half8 h;
    h[0] = (_Float16)a0.x; h[1] = (_Float16)a0.y; h[2] = (_Float16)a0.z; h[3] = (_Float16)a0.w;
    h[4] = (_Float16)a1.x; h[5] = (_Float16)a1.y; h[6] = (_Float16)a1.z; h[7] = (_Float16)a1.w;
    return h;
}

__device__ __forceinline__ void gload_lds16(const _Float16* g, _Float16* l) {
    __builtin_amdgcn_global_load_lds(
        (const __attribute__((address_space(1))) void*)g,
        (__attribute__((address_space(3))) void*)l, 16, 0, 0);
}

// BM=64 x BN=256, BK=32. 4 waves; wave w owns 64-col quarter, acc[2][2].
// A staged coalesced->LDS (pad-40 rows), B via global_load_lds from
// PRE-SWIZZLED blocked panel (linear dest + inv-swz source + swz read).
// C/D: col=lane&31, row=(reg&3)+8*(reg>>2)+4*(lane>>5)  [m74/m101-verified].
template <int K, typename AT>
__device__ __forceinline__ void gemm_body(const AT* __restrict__ A,
                                          const _Float16* __restrict__ Bblk,
                                          _Float16* __restrict__ C, int M, int bid) {
    __shared__ _Float16 sA[64 * 40];    // pad 32->40 halves per row
    __shared__ _Float16 sB[256 * 32];   // swizzled blocked tile (16KB)
    int t = threadIdx.x, lane = t & 63, w = t >> 6;
    int l31 = lane & 31, hi = lane >> 5;
    int m0 = bid * 64;
    int r = t >> 2, sg = t & 3;
    int arow = min(m0 + r, M - 1);                 // clamp: no OOB reads
    const AT* ap = A + (size_t)arow * K + sg * 8;
    const _Float16* gpb = Bblk + w * 2048 + lane * 8;
    _Float16* lpb = &sB[w * 2048];
    int n0 = w * 64 + l31, n1 = n0 + 32;
    int bo0 = n0 * 32, bo1 = n1 * 32;
    int sw0 = (n0 & 3) << 3, sw1 = (n1 & 3) << 3;

    f32x16 acc[2][2];
    #pragma unroll
    for (int mf = 0; mf < 2; ++mf)
        #pragma unroll
        for (int nf = 0; nf < 2; ++nf)
            #pragma unroll
            for (int s = 0; s < 16; ++s) acc[mf][nf][s] = 0.f;

    for (int k0 = 0; k0 < K; k0 += 32) {
        const _Float16* gp = gpb + (k0 >> 5) * 8192;
        #pragma unroll
        for (int i = 0; i < 4; ++i)
            gload_lds16(gp + i * 512, lpb + i * 512);
        half8 av = load_a8(ap + k0);
        *(half8*)&sA[r * 40 + sg * 8] = av;
        __syncthreads();
        #pragma unroll
        for (int kk = 0; kk < 2; ++kk) {
            int g8 = (kk * 2 + hi) << 3;
            half8 af0 = *(const half8*)&sA[l31 * 40 + g8];
            half8 af1 = *(const half8*)&sA[(l31 + 32) * 40 + g8];
            half8 bf0 = *(const half8*)&sB[bo0 + (g8 ^ sw0)];
            half8 bf1 = *(const half8*)&sB[bo1 + (g8 ^ sw1)];
            acc[0][0] = __builtin_amdgcn_mfma_f32_32x32x16_f16(af0, bf0, acc[0][0], 0, 0, 0);
            acc[0][1] = __builtin_amdgcn_mfma_f32_32x32x16_f16(af0, bf1, acc[0][1], 0, 0, 0);
            acc[1][0] = __builtin_amdgcn_mfma_f32_32x32x16_f16(af1, bf0, acc[1][0], 0, 0, 0);
            acc[1][1] = __builtin_amdgcn_mfma_f32_32x32x16_f16(af1, bf1, acc[1][1], 0, 0, 0);
        }
        __syncthreads();
    }
    int mbase = m0 + 4 * hi;
    #pragma unroll
    for (int mf = 0; mf < 2; ++mf)
        #pragma unroll
        for (int nf = 0; nf < 2; ++nf) {
            int n = w * 64 + nf * 32 + l31;
            #pragma unroll
            for (int rr = 0; rr < 16; ++rr) {
                int m = mbase + mf * 32 + (rr & 3) + 8 * (rr >> 2);
                if (m < M) C[(size_t)m * HID_C + n] = (_Float16)acc[mf][nf][rr];
            }
        }
}

// wave per node, lane = 4 channels (half4 = 8 B); ELL rows, MLP-8.
// nv = w * dinv[col] computed in-loop (dinv is 200KB, L2-resident broadcast);
// result scaled by dinv[row] at the end. Identical fp32 ops as pre-scaling.
__device__ __forceinline__ void prop256_body(const _Float16* __restrict__ h,
                                             _Float16* __restrict__ out,
                                             const float* __restrict__ bias, int bid) {
    int wv = threadIdx.x >> 6, lane = threadIdx.x & 63;
    int i = bid * 4 + wv;
    const half4v* hv = (const half4v*)h;
    float di = g_dinv[i];
    half4v r = hv[(size_t)i * 64 + lane];
    float4 acc = make_float4(di * (float)r.x, di * (float)r.y,
                             di * (float)r.z, di * (float)r.w);
    int cnt = min(g_fill[i], ELL_CAP);
    const ull* ep = (const ull*)(g_ell + (size_t)i * ELL_CAP);
    int k = 0;
    for (; k + 8 <= cnt; k += 8) {
        ull raw[8];
        #pragma unroll
        for (int j = 0; j < 8; ++j) raw[j] = ep[k + j];
        float dc[8];
        #pragma unroll
        for (int j = 0; j < 8; ++j) dc[j] = g_dinv[(unsigned)(raw[j] & 0xffffffffu)];
        half4v v[8];
        #pragma unroll
        for (int j = 0; j < 8; ++j)
            v[j] = hv[(size_t)(unsigned)(raw[j] & 0xffffffffu) * 64 + lane];
        #pragma unroll
        for (int j = 0; j < 8; ++j) {
            float nv = __int_as_float((int)(raw[j] >> 32)) * dc[j];
            acc.x += nv * (float)v[j].x; acc.y += nv * (float)v[j].y;
            acc.z += nv * (float)v[j].z; acc.w += nv * (float)v[j].w;
        }
    }
    for (; k < cnt; ++k) {
        ull raw = ep[k];
        unsigned c = (unsigned)(raw & 0xffffffffu);
        float nv = __int_as_float((int)(raw >> 32)) * g_dinv[c];
        half4v v = hv[(size_t)c * 64 + lane];
        acc.x += nv * (float)v.x; acc.y += nv * (float)v.y;
        acc.z += nv * (float)v.z; acc.w += nv * (float)v.w;
    }
    float4 b = ((const float4*)bias)[lane];
    half4v o;
    o.x = (_Float16)(di * acc.x + b.x); o.y = (_Float16)(di * acc.y + b.y);
    o.z = (_Float16)(di * acc.z + b.z); o.w = (_Float16)(di * acc.w + b.w);
    ((half4v*)out)[(size_t)i * 64 + lane] = o;
}

// paired label propagation on interleaved fp16 [i][80]; lane = half2 (2 chans)
template <bool FINAL>
__device__ __forceinline__ void prop80_body(const _Float16* __restrict__ y,
                                            _Float16* __restrict__ o,
                                            float* __restrict__ o1,
                                            float* __restrict__ o2, int bid) {
    int wv = threadIdx.x >> 6, lane = threadIdx.x & 63;
    if (lane >= 40) return;
    int i = bid * 4 + wv;
    const half2v* yp = (const half2v*)y;
    float di = g_dinv[i];
    half2v sv = yp[(size_t)i * 40 + lane];
    float a0 = di * (float)sv.x, a1 = di * (float)sv.y;
    int cnt = min(g_fill[i], ELL_CAP);
    const ull* ep = (const ull*)(g_ell + (size_t)i * ELL_CAP);
    int k = 0;
    for (; k + 8 <= cnt; k += 8) {
        ull raw[8];
        #pragma unroll
        for (int j = 0; j < 8; ++j) raw[j] = ep[k + j];
        float dc[8];
        #pragma unroll
        for (int j = 0; j < 8; ++j) dc[j] = g_dinv[(unsigned)(raw[j] & 0xffffffffu)];
        half2v v[8];
        #pragma unroll
        for (int j = 0; j < 8; ++j)
            v[j] = yp[(size_t)(unsigned)(raw[j] & 0xffffffffu) * 40 + lane];
        #pragma unroll
        for (int j = 0; j < 8; ++j) {
            float nv = __int_as_float((int)(raw[j] >> 32)) * dc[j];
            a0 += nv * (float)v[j].x; a1 += nv * (float)v[j].y;
        }
    }
    for (; k < cnt; ++k) {
        ull raw = ep[k];
        unsigned c = (unsigned)(raw & 0xffffffffu);
        float nv = __int_as_float((int)(raw >> 32)) * g_dinv[c];
        half2v v = yp[(size_t)c * 40 + lane];
        a0 += nv * (float)v.x; a1 += nv * (float)v.y;
    }
    if (FINAL) {
        int cc = lane * 2;
        float vals[2] = {di * a0, di * a1};
        #pragma unroll
        for (int t = 0; t < 2; ++t) {
            int c = cc + t;
            if (c < OUT_C) o1[(size_t)i * OUT_C + c] = vals[t];
            else           o2[(size_t)i * OUT_C + (c - OUT_C)] = vals[t];
        }
    } else {
        half2v ov; ov.x = (_Float16)(di * a0); ov.y = (_Float16)(di * a1);
        ((half2v*)o)[(size_t)i * 40 + lane] = ov;
    }
}

__device__ __forceinline__ void prop40_body(const _Float16* __restrict__ h,
                                            float* __restrict__ out,
                                            const float* __restrict__ bias, int bid) {
    int wv = threadIdx.x >> 6, lane = threadIdx.x & 63;
    if (lane >= OUT_C) return;
    int i = bid * 4 + wv;
    float di = g_dinv[i];
    float acc = di * (float)h[(size_t)i * OUT_C + lane];
    int cnt = min(g_fill[i], ELL_CAP);
    const ull* ep = (const ull*)(g_ell + (size_t)i * ELL_CAP);
    int k = 0;
    for (; k + 8 <= cnt; k += 8) {
        ull raw[8];
        #pragma unroll
        for (int j = 0; j < 8; ++j) raw[j] = ep[k + j];
        float dc[8];
        #pragma unroll
        for (int j = 0; j < 8; ++j) dc[j] = g_dinv[(unsigned)(raw[j] & 0xffffffffu)];
        float v[8];
        #pragma unroll
        for (int j = 0; j < 8; ++j)
            v[j] = (float)h[(size_t)(unsigned)(raw[j] & 0xffffffffu) * OUT_C + lane];
        #pragma unroll
        for (int j = 0; j < 8; ++j)
            acc += __int_as_float((int)(raw[j] >> 32)) * dc[j] * v[j];
    }
    for (; k < cnt; ++k) {
        ull raw = ep[k];
        unsigned c = (unsigned)(raw & 0xffffffffu);
        acc += __int_as_float((int)(raw >> 32)) * g_dinv[c]
             * (float)h[(size_t)c * OUT_C + lane];
    }
    out[(size_t)i * OUT_C + lane] = di * acc + bias[lane];
}

// ---------------- fused co-launch kernels (striped block mapping) ----------
// F0: 1 gemm : 24 {fill,cvt} per 25 blocks. bijective r = b - b/25 - 1.
__global__ __launch_bounds__(256) void fused0(const float* __restrict__ x,
                                              const int* __restrict__ ei,
                                              const float* __restrict__ ew,
                                              const float* __restrict__ lab1,
                                              const float* __restrict__ lab2) {
    int b = blockIdx.x;
    int q = b / 25;
    if (b - q * 25 == 0) { gemm_body<IN_C, float>(x, g_w0t, g_Ah, N_NODES, q); return; }
    int r = b - q - 1;                 // contiguous 0..24*q+23 within stripes
    if (r < EB)              fill_body(ei, ei + N_EDGES, ew, r);
    else if (r < EB + CVTB)  cvt_body(lab1, lab2, g_l80a, r - EB);
}

// P1: GCN prop layer-0 || LPA pass 1  (even/odd stripe)
__global__ __launch_bounds__(256) void fused_p1(const float* __restrict__ b0) {
    int b = blockIdx.x;
    if ((b & 1) == 0) prop256_body(g_Ah, g_P, b0, b >> 1);
    else              prop80_body<false>(g_l80a, g_l80b, nullptr, nullptr, b >> 1);
}

// G1: 1 gemm : 16 prop80 per 17 blocks
__global__ __launch_bounds__(256) void fused_g1() {
    int b = blockIdx.x;
    int q = b / 17;
    if (b - q * 17 == 0) { gemm_body<HID_C, _Float16>(g_h16, g_w1t, g_Ah, N_NODES, q); return; }
    int p = b - q - 1;
    if (p < PB) prop80_body<false>(g_l80b, g_l80a, nullptr, nullptr, p);
}

// P2: GCN prop layer-1 || LPA pass 3 (final, writes d_out)
__global__ __launch_bounds__(256) void fused_p2(const float* __restrict__ b1,
                                                float* __restrict__ o1,
                                                float* __restrict__ o2) {
    int b = blockIdx.x;
    if ((b & 1) == 0) prop256_body(g_Ah, g_P, b1, b >> 1);
    else              prop80_body<true>(g_l80a, nullptr, o1, o2, b >> 1);
}

__global__ __launch_bounds__(256) void prop40h(const float* __restrict__ bias,
                                               float* __restrict__ out) {
    prop40_body(g_o40h, out, bias, blockIdx.x);
}

// ---------------- graph small kernels ----------------
__global__ __launch_bounds__(256) void deg_dinv() {
    int i = blockIdx.x * blockDim.x + threadIdx.x;
    if (i >= N_NODES) return;
    int cnt = min(g_fill[i], ELL_CAP);
    const int2* ep = g_ell + (size_t)i * ELL_CAP;
    float s = 0.f;
    for (int p = 0; p < cnt; ++p) s += __int_as_float(ep[p].y);
    float d = s + 1.0f;   // + self-loop weight 1
    g_dinv[i] = (d > 0.f) ? rsqrtf(fmaxf(d, 1e-12f)) : 0.f;
}

// ---------------- conversions ----------------
__global__ void wtrans_blk(const float* __restrict__ W, _Float16* __restrict__ dst, int K) {
    int idx = blockIdx.x * blockDim.x + threadIdx.x;
    if (idx >= K * 256) return;
    int k = idx >> 8, n = idx & 255;
    int t = k >> 5, kl = k & 31, g = kl >> 3, j = kl & 7;
    dst[t * 8192 + n * 32 + ((g ^ (n & 3)) << 3) + j] = (_Float16)W[(size_t)k * 256 + n];
}

__global__ void wtrans_out(const float* __restrict__ W, _Float16* __restrict__ dst) {
    int idx = blockIdx.x * blockDim.x + threadIdx.x;
    if (idx >= 256 * 64) return;
    int k = idx >> 6, n = idx & 63;
    int g = k >> 3, j = k & 7;
    float v = (n < OUT_C) ? W[(size_t)k * OUT_C + n] : 0.f;
    dst[n * 256 + ((g ^ (n & 7)) << 3) + j] = (_Float16)v;
}

// BN scale/shift + ReLU on fp16: g_P -> g_h16
__global__ __launch_bounds__(256) void bn_apply16(const _Float16* __restrict__ h,
                                                  _Float16* __restrict__ out,
                                                  const float* __restrict__ scale,
                                                  const float* __restrict__ shift) {
    int i = blockIdx.x * blockDim.x + threadIdx.x;   // half4-group index
    if (i >= N_NODES * (HID_C / 4)) return;
    int c = (i & 63) * 4;
    half4v v = ((const half4v*)h)[i];
    half4v o;
    o.x = (_Float16)fmaxf((float)v.x * scale[c + 0] + shift[c + 0], 0.f);
    o.y = (_Float16)fmaxf((float)v.y * scale[c + 1] + shift[c + 1], 0.f);
    o.z = (_Float16)fmaxf((float)v.z * scale[c + 2] + shift[c + 2], 0.f);
    o.w = (_Float16)fmaxf((float)v.w * scale[c + 3] + shift[c + 3], 0.f);
    ((half4v*)out)[i] = o;
}

// Out layer: BM=128 (wave w -> 32 rows), N=40 (padded 64). Whole 32KB B panel
// staged to LDS once, A staged per-BK=32 step.
__global__ __launch_bounds__(256) void gemm_out_t(const _Float16* __restrict__ A,
                                                  const _Float16* __restrict__ Bblk,
                                                  _Float16* __restrict__ C, int M) {
    __shared__ _Float16 sB[64 * 256];   // 32KB, swizzled
    __shared__ _Float16 sA[128 * 40];   // 10KB
    const int K = HID_C;
    int t = threadIdx.x, lane = t & 63, w = t >> 6;
    int l31 = lane & 31, hi = lane >> 5;
    int m0 = blockIdx.x * 128;
    {   // stage whole B once (async)
        const _Float16* gp = Bblk + w * 4096 + lane * 8;
        _Float16* lp = &sB[w * 4096];
        #pragma unroll
        for (int i = 0; i < 8; ++i)
            gload_lds16(gp + i * 512, lp + i * 512);
    }
    f32x16 acc[2];
    #pragma unroll
    for (int nf = 0; nf < 2; ++nf)
        #pragma unroll
        for (int s = 0; s < 16; ++s) acc[nf][s] = 0.f;

    for (int k0 = 0; k0 < K; k0 += 32) {
        #pragma unroll
        for (int u = 0; u < 2; ++u) {
            int uu = t + u * 256;
            int r = uu >> 2, sg = uu & 3;
            int arow = min(m0 + r, M - 1);
            half8 av = *(const half8*)(A + (size_t)arow * K + k0 + sg * 8);
            *(half8*)&sA[r * 40 + sg * 8] = av;
        }
        __syncthreads();
        #pragma unroll
        for (int kk = 0; kk < 2; ++kk) {
            int gloc = kk * 2 + hi;
            int g = (k0 >> 3) + gloc;
            half8 af = *(const half8*)&sA[(w * 32 + l31) * 40 + gloc * 8];
            #pragma unroll
            for (int nf = 0; nf < 2; ++nf) {
                int n = nf * 32 + l31;
                half8 bf = *(const half8*)&sB[n * 256 + ((g ^ (n & 7)) << 3)];
                acc[nf] = __builtin_amdgcn_mfma_f32_32x32x16_f16(af, bf, acc[nf], 0, 0, 0);
            }
        }
        __syncthreads();
    }
    int mbase = m0 + w * 32 + 4 * hi;
    #pragma unroll
    for (int nf = 0; nf < 2; ++nf) {
        int n = nf * 32 + l31;
        if (n < OUT_C) {
            #pragma unroll
            for (int rr = 0; rr < 16; ++rr) {
                int m = mbase + (rr & 3) + 8 * (rr >> 2);
                if (m < M) C[(size_t)m * OUT_C + n] = (_Float16)acc[nf][rr];
            }
        }
    }
}

// ---------------- batchnorm stats (fp16 input, 32 rows/block) ----------------
__global__ __launch_bounds__(256) void bn_stats16(const _Float16* __restrict__ h, int layer) {
    int c = threadIdx.x;
    int r0 = blockIdx.x * 32;
    int rend = min(r0 + 32, N_NODES);
    float s = 0.f, ss = 0.f;
    for (int i = r0; i < rend; ++i) {
        float v = (float)h[(size_t)i * HID_C + c];
        s += v; ss += v * v;
    }
    atomicAdd(&g_bnstat[layer * 512 + c], s);
    atomicAdd(&g_bnstat[layer * 512 + 256 + c], ss);
}

__global__ void bn_final(int layer, const float* __restrict__ gamma,
                         const float* __restrict__ beta) {
    int c = threadIdx.x;
    float sum = g_bnstat[layer * 512 + c];
    float ss  = g_bnstat[layer * 512 + 256 + c];
    float mu  = sum / (float)N_NODES;
    float var = fmaxf(ss / (float)N_NODES - mu * mu, 0.f);
    float scale = gamma[c] * rsqrtf(var + BN_EPS);
    g_bnss[layer * 512 + c]       = scale;
    g_bnss[layer * 512 + 256 + c] = beta[c] - mu * scale;
}

// ---------------- host ----------------
template <typename T>
static T* symaddr(const void* sym) {
    void* p = nullptr;
    (void)hipGetSymbolAddress(&p, sym);
    return (T*)p;
}

extern "C" void kernel_launch(void* const* d_in, const int* in_sizes, int n_in,
                              void* d_out, int out_size, void* d_ws, size_t ws_size,
                              hipStream_t stream) {
    const float* x    = (const float*)d_in[0];
    const int*   ei   = (const int*)d_in[1];
    const float* lab1 = (const float*)d_in[2];
    const float* lab2 = (const float*)d_in[3];
    const float* ew   = (const float*)d_in[4];
    const float* W0   = (const float*)d_in[5];
    const float* b0   = (const float*)d_in[6];
    const float* W1   = (const float*)d_in[7];
    const float* b1   = (const float*)d_in[8];
    const float* W2   = (const float*)d_in[9];
    const float* b2   = (const float*)d_in[10];
    const float* gg0  = (const float*)d_in[11];
    const float* be0  = (const float*)d_in[12];
    const float* gg1  = (const float*)d_in[13];
    const float* be1  = (const float*)d_in[14];

    _Float16* ph16 = symaddr<_Float16>(HIP_SYMBOL(g_h16));
    _Float16* pP   = symaddr<_Float16>(HIP_SYMBOL(g_P));
    _Float16* po40 = symaddr<_Float16>(HIP_SYMBOL(g_o40h));
    _Float16* pw0t = symaddr<_Float16>(HIP_SYMBOL(g_w0t));
    _Float16* pw1t = symaddr<_Float16>(HIP_SYMBOL(g_w1t));
    _Float16* pw2t = symaddr<_Float16>(HIP_SYMBOL(g_w2t));
    int*   pfil = symaddr<int>(HIP_SYMBOL(g_fill));
    float* pbst = symaddr<float>(HIP_SYMBOL(g_bnstat));
    float* pbss = symaddr<float>(HIP_SYMBOL(g_bnss));

    hipMemsetAsync(pfil, 0, N_NODES * sizeof(int),   stream);
    hipMemsetAsync(pbst, 0, 4 * HID_C * sizeof(float), stream);

    // weight transposes (blocked+swizzled); W0 must precede fused0's gemm
    wtrans_blk<<<(IN_C * 256 + 255) / 256, 256, 0, stream>>>(W0, pw0t, IN_C);
    wtrans_blk<<<(HID_C * 256 + 255) / 256, 256, 0, stream>>>(W1, pw1t, HID_C);
    wtrans_out<<<(256 * 64 + 255) / 256, 256, 0, stream>>>(W2, pw2t);

    const int GB32 = (N_NODES + 31) / 32;    // 1563
    const int CB   = (N_NODES * 64 + 255) / 256;
    float* outf = (float*)d_out;    // fp32: out | y_hat | y_hat2

    // F0: gemm layer-0 || ELL fill || label convert (striped 1:24)
    fused0<<<GT64 * 25, 256, 0, stream>>>(x, ei, ew, lab1, lab2);
    deg_dinv<<<(N_NODES + 255) / 256, 256, 0, stream>>>();

    // P1: prop layer-0 || LPA pass 1 (even/odd)
    fused_p1<<<PB + PB, 256, 0, stream>>>(b0);
    bn_stats16<<<GB32, 256, 0, stream>>>(pP, 0);
    bn_final<<<1, 256, 0, stream>>>(0, gg0, be0);
    bn_apply16<<<CB, 256, 0, stream>>>(pP, ph16, pbss, pbss + 256);

    // G1: gemm layer-1 || LPA pass 2 (striped 1:16)
    fused_g1<<<GT64 * 17, 256, 0, stream>>>();

    // P2: prop layer-1 || LPA pass 3 (final)
    fused_p2<<<PB + PB, 256, 0, stream>>>(b1,
                                          outf + (size_t)N_NODES * OUT_C,
                                          outf + 2 * (size_t)N_NODES * OUT_C);
    bn_stats16<<<GB32, 256, 0, stream>>>(pP, 1);
    bn_final<<<1, 256, 0, stream>>>(1, gg1, be1);
    bn_apply16<<<CB, 256, 0, stream>>>(pP, ph16, pbss + 512, pbss + 768);

    // layer 2
    gemm_out_t<<<(N_NODES + 127) / 128, 256, 0, stream>>>(ph16, pw2t, po40, N_NODES);
    prop40h<<<PB, 256, 0, stream>>>(b2, outf);
}

// Round 8
// 743.995 us; speedup vs baseline: 1.0493x; 1.0493x over previous
//
#include <hip/hip_runtime.h>

#define N_NODES 50000
#define N_EDGES 800000
#define IN_C    512
#define HID_C   256
#define OUT_C   40
#define BN_EPS  1e-5f
#define ELL_CAP 64
#define GT64    782      // ceil(N_NODES/64)
#define FB4     782      // ceil(N_EDGES/1024)  (fill: 4 edges/thread)
#define CVT4    3907     // ceil(N_NODES*20/256) (cvt: half4 groups)
#define PB      12500    // N_NODES/4

typedef _Float16 half2v __attribute__((ext_vector_type(2)));
typedef _Float16 half4v __attribute__((ext_vector_type(4)));
typedef _Float16 half8  __attribute__((ext_vector_type(8)));
typedef float    f32x16 __attribute__((ext_vector_type(16)));
typedef unsigned long long ull;

// ---------------- static device buffers ----------------
__device__ _Float16 g_h16 [(size_t)N_NODES * HID_C]; // BN+ReLU'd hidden (fp16)
__device__ _Float16 g_Ah  [(size_t)N_NODES * HID_C]; // gemm out (fp16)
__device__ _Float16 g_P   [(size_t)N_NODES * HID_C]; // prop out (fp16, pre-BN)
__device__ _Float16 g_o40h[(size_t)N_NODES * OUT_C]; // out-layer gemm (fp16)
__device__ _Float16 g_l80a[(size_t)N_NODES * 80];    // labels interleaved y1|y2 fp16
__device__ _Float16 g_l80b[(size_t)N_NODES * 80];
__device__ _Float16 g_w0t[HID_C * IN_C];             // W0^T blocked+swizzled [K/32][256][32]
__device__ _Float16 g_w1t[HID_C * HID_C];            // W1^T blocked+swizzled
__device__ _Float16 g_w2t[64 * HID_C];               // W2^T swizzled [64][256]
__device__ int2  g_ell[(size_t)N_NODES * ELL_CAP];   // padded edge slots {col, raw w bits}
__device__ int   g_fill[N_NODES];                    // per-row fill count (= degree)
__device__ float g_dinv[N_NODES];
__device__ float g_bnstat[4 * HID_C];                // sum0|ss0|sum1|ss1
__device__ float g_bnss  [4 * HID_C];                // scale0|shift0|scale1|shift1

// ---------------- device bodies (indexing via explicit bid) ----------------
// fill: 4 edges/thread — 4 independent atomicAdds in flight before the
// dependent scattered stores (MLP on the ~600-900cy atomic return latency).
__device__ __forceinline__ void fill4_body(const int* __restrict__ row,
                                           const int* __restrict__ col,
                                           const float* __restrict__ w, int bid) {
    int base = bid * 1024 + threadIdx.x;
    int r[4], c[4]; float wv[4]; bool ok[4];
    #pragma unroll
    for (int u = 0; u < 4; ++u) {
        int e = base + u * 256;
        ok[u] = (e < N_EDGES);
        if (ok[u]) { r[u] = row[e]; c[u] = col[e]; wv[u] = w[e]; }
    }
    int pos[4];
    #pragma unroll
    for (int u = 0; u < 4; ++u)
        if (ok[u]) pos[u] = atomicAdd(&g_fill[r[u]], 1);
    #pragma unroll
    for (int u = 0; u < 4; ++u)
        if (ok[u] && pos[u] < ELL_CAP)   // deg ~ Poisson(16): guard only
            g_ell[(size_t)r[u] * ELL_CAP + pos[u]] = make_int2(c[u], __float_as_int(wv[u]));
}

// labels -> interleaved fp16 [i][80] = y1|y2, half4-vectorized (float4 loads).
// group g in [0,20): out offset i*80 + g*4 (g>=10 lands at 40+(g-10)*4 = g*4).
__device__ __forceinline__ void cvt4_body(const float* __restrict__ lab1,
                                          const float* __restrict__ lab2,
                                          _Float16* __restrict__ out, int bid) {
    int idx = bid * 256 + threadIdx.x;
    if (idx >= N_NODES * 20) return;
    int i = idx / 20, g = idx - 20 * i;
    const float* src = (g < 10) ? lab1 + (size_t)i * 40 + g * 4
                                : lab2 + (size_t)i * 40 + (g - 10) * 4;
    float4 v = *(const float4*)src;
    half4v o;
    o.x = (_Float16)v.x; o.y = (_Float16)v.y; o.z = (_Float16)v.z; o.w = (_Float16)v.w;
    ((half4v*)out)[(size_t)i * 20 + g] = o;
}

__device__ __forceinline__ half8 load_a8(const _Float16* p) { return *(const half8*)p; }
__device__ __forceinline__ half8 load_a8(const float* p) {
    float4 a0 = *(const float4*)p;
    float4 a1 = *(const float4*)(p + 4);
    half8 h;
    h[0] = (_Float16)a0.x; h[1] = (_Float16)a0.y; h[2] = (_Float16)a0.z; h[3] = (_Float16)a0.w;
    h[4] = (_Float16)a1.x; h[5] = (_Float16)a1.y; h[6] = (_Float16)a1.z; h[7] = (_Float16)a1.w;
    return h;
}

__device__ __forceinline__ void gload_lds16(const _Float16* g, _Float16* l) {
    __builtin_amdgcn_global_load_lds(
        (const __attribute__((address_space(1))) void*)g,
        (__attribute__((address_space(3))) void*)l, 16, 0, 0);
}

// BM=64 x BN=256, BK=32. 4 waves; wave w owns 64-col quarter, acc[2][2].
// A staged coalesced->LDS (pad-40 rows), B via global_load_lds from
// PRE-SWIZZLED blocked panel (linear dest + inv-swz source + swz read).
// C/D: col=lane&31, row=(reg&3)+8*(reg>>2)+4*(lane>>5)  [m74/m101-verified].
template <int K, typename AT>
__device__ __forceinline__ void gemm_body(const AT* __restrict__ A,
                                          const _Float16* __restrict__ Bblk,
                                          _Float16* __restrict__ C, int M, int bid) {
    __shared__ _Float16 sA[64 * 40];    // pad 32->40 halves per row
    __shared__ _Float16 sB[256 * 32];   // swizzled blocked tile (16KB)
    int t = threadIdx.x, lane = t & 63, w = t >> 6;
    int l31 = lane & 31, hi = lane >> 5;
    int m0 = bid * 64;
    int r = t >> 2, sg = t & 3;
    int arow = min(m0 + r, M - 1);                 // clamp: no OOB reads
    const AT* ap = A + (size_t)arow * K + sg * 8;
    const _Float16* gpb = Bblk + w * 2048 + lane * 8;
    _Float16* lpb = &sB[w * 2048];
    int n0 = w * 64 + l31, n1 = n0 + 32;
    int bo0 = n0 * 32, bo1 = n1 * 32;
    int sw0 = (n0 & 3) << 3, sw1 = (n1 & 3) << 3;

    f32x16 acc[2][2];
    #pragma unroll
    for (int mf = 0; mf < 2; ++mf)
        #pragma unroll
        for (int nf = 0; nf < 2; ++nf)
            #pragma unroll
            for (int s = 0; s < 16; ++s) acc[mf][nf][s] = 0.f;

    for (int k0 = 0; k0 < K; k0 += 32) {
        const _Float16* gp = gpb + (k0 >> 5) * 8192;
        #pragma unroll
        for (int i = 0; i < 4; ++i)
            gload_lds16(gp + i * 512, lpb + i * 512);
        half8 av = load_a8(ap + k0);
        *(half8*)&sA[r * 40 + sg * 8] = av;
        __syncthreads();
        #pragma unroll
        for (int kk = 0; kk < 2; ++kk) {
            int g8 = (kk * 2 + hi) << 3;
            half8 af0 = *(const half8*)&sA[l31 * 40 + g8];
            half8 af1 = *(const half8*)&sA[(l31 + 32) * 40 + g8];
            half8 bf0 = *(const half8*)&sB[bo0 + (g8 ^ sw0)];
            half8 bf1 = *(const half8*)&sB[bo1 + (g8 ^ sw1)];
            acc[0][0] = __builtin_amdgcn_mfma_f32_32x32x16_f16(af0, bf0, acc[0][0], 0, 0, 0);
            acc[0][1] = __builtin_amdgcn_mfma_f32_32x32x16_f16(af0, bf1, acc[0][1], 0, 0, 0);
            acc[1][0] = __builtin_amdgcn_mfma_f32_32x32x16_f16(af1, bf0, acc[1][0], 0, 0, 0);
            acc[1][1] = __builtin_amdgcn_mfma_f32_32x32x16_f16(af1, bf1, acc[1][1], 0, 0, 0);
        }
        __syncthreads();
    }
    int mbase = m0 + 4 * hi;
    #pragma unroll
    for (int mf = 0; mf < 2; ++mf)
        #pragma unroll
        for (int nf = 0; nf < 2; ++nf) {
            int n = w * 64 + nf * 32 + l31;
            #pragma unroll
            for (int rr = 0; rr < 16; ++rr) {
                int m = mbase + mf * 32 + (rr & 3) + 8 * (rr >> 2);
                if (m < M) C[(size_t)m * HID_C + n] = (_Float16)acc[mf][nf][rr];
            }
        }
}

// wave per node, lane = 4 channels (half4 = 8 B); ELL rows, MLP-8.
// nv = w * dinv[col] in-loop (dinv L2-resident broadcast); result × dinv[row].
__device__ __forceinline__ void prop256_body(const _Float16* __restrict__ h,
                                             _Float16* __restrict__ out,
                                             const float* __restrict__ bias, int bid) {
    int wv = threadIdx.x >> 6, lane = threadIdx.x & 63;
    int i = bid * 4 + wv;
    const half4v* hv = (const half4v*)h;
    float di = g_dinv[i];
    half4v r = hv[(size_t)i * 64 + lane];
    float4 acc = make_float4(di * (float)r.x, di * (float)r.y,
                             di * (float)r.z, di * (float)r.w);
    int cnt = min(g_fill[i], ELL_CAP);
    const ull* ep = (const ull*)(g_ell + (size_t)i * ELL_CAP);
    int k = 0;
    for (; k + 8 <= cnt; k += 8) {
        ull raw[8];
        #pragma unroll
        for (int j = 0; j < 8; ++j) raw[j] = ep[k + j];
        float dc[8];
        #pragma unroll
        for (int j = 0; j < 8; ++j) dc[j] = g_dinv[(unsigned)(raw[j] & 0xffffffffu)];
        half4v v[8];
        #pragma unroll
        for (int j = 0; j < 8; ++j)
            v[j] = hv[(size_t)(unsigned)(raw[j] & 0xffffffffu) * 64 + lane];
        #pragma unroll
        for (int j = 0; j < 8; ++j) {
            float nv = __int_as_float((int)(raw[j] >> 32)) * dc[j];
            acc.x += nv * (float)v[j].x; acc.y += nv * (float)v[j].y;
            acc.z += nv * (float)v[j].z; acc.w += nv * (float)v[j].w;
        }
    }
    for (; k < cnt; ++k) {
        ull raw = ep[k];
        unsigned c = (unsigned)(raw & 0xffffffffu);
        float nv = __int_as_float((int)(raw >> 32)) * g_dinv[c];
        half4v v = hv[(size_t)c * 64 + lane];
        acc.x += nv * (float)v.x; acc.y += nv * (float)v.y;
        acc.z += nv * (float)v.z; acc.w += nv * (float)v.w;
    }
    float4 b = ((const float4*)bias)[lane];
    half4v o;
    o.x = (_Float16)(di * acc.x + b.x); o.y = (_Float16)(di * acc.y + b.y);
    o.z = (_Float16)(di * acc.z + b.z); o.w = (_Float16)(di * acc.w + b.w);
    ((half4v*)out)[(size_t)i * 64 + lane] = o;
}

// paired label propagation on interleaved fp16 [i][80]; lane = half2 (2 chans)
template <bool FINAL>
__device__ __forceinline__ void prop80_body(const _Float16* __restrict__ y,
                                            _Float16* __restrict__ o,
                                            float* __restrict__ o1,
                                            float* __restrict__ o2, int bid) {
    int wv = threadIdx.x >> 6, lane = threadIdx.x & 63;
    if (lane >= 40) return;
    int i = bid * 4 + wv;
    const half2v* yp = (const half2v*)y;
    float di = g_dinv[i];
    half2v sv = yp[(size_t)i * 40 + lane];
    float a0 = di * (float)sv.x, a1 = di * (float)sv.y;
    int cnt = min(g_fill[i], ELL_CAP);
    const ull* ep = (const ull*)(g_ell + (size_t)i * ELL_CAP);
    int k = 0;
    for (; k + 8 <= cnt; k += 8) {
        ull raw[8];
        #pragma unroll
        for (int j = 0; j < 8; ++j) raw[j] = ep[k + j];
        float dc[8];
        #pragma unroll
        for (int j = 0; j < 8; ++j) dc[j] = g_dinv[(unsigned)(raw[j] & 0xffffffffu)];
        half2v v[8];
        #pragma unroll
        for (int j = 0; j < 8; ++j)
            v[j] = yp[(size_t)(unsigned)(raw[j] & 0xffffffffu) * 40 + lane];
        #pragma unroll
        for (int j = 0; j < 8; ++j) {
            float nv = __int_as_float((int)(raw[j] >> 32)) * dc[j];
            a0 += nv * (float)v[j].x; a1 += nv * (float)v[j].y;
        }
    }
    for (; k < cnt; ++k) {
        ull raw = ep[k];
        unsigned c = (unsigned)(raw & 0xffffffffu);
        float nv = __int_as_float((int)(raw >> 32)) * g_dinv[c];
        half2v v = yp[(size_t)c * 40 + lane];
        a0 += nv * (float)v.x; a1 += nv * (float)v.y;
    }
    if (FINAL) {
        int cc = lane * 2;
        float vals[2] = {di * a0, di * a1};
        #pragma unroll
        for (int t = 0; t < 2; ++t) {
            int c = cc + t;
            if (c < OUT_C) o1[(size_t)i * OUT_C + c] = vals[t];
            else           o2[(size_t)i * OUT_C + (c - OUT_C)] = vals[t];
        }
    } else {
        half2v ov; ov.x = (_Float16)(di * a0); ov.y = (_Float16)(di * a1);
        ((half2v*)o)[(size_t)i * 40 + lane] = ov;
    }
}

// GCN output: 2 nodes/wave, lane = half2 group (4B gathers, 2 rows in flight).
// lanes 0-19 -> node bid*8+wv*2, lanes 32-51 -> +1. float2 out stores.
__device__ __forceinline__ void prop40_body(const _Float16* __restrict__ h,
                                            float* __restrict__ out,
                                            const float* __restrict__ bias, int bid) {
    int wv = threadIdx.x >> 6, lane = threadIdx.x & 63;
    int g = lane & 31;
    if (g >= 20) return;
    int i = bid * 8 + wv * 2 + (lane >> 5);
    const half2v* hp = (const half2v*)h;
    float di = g_dinv[i];
    half2v sv = hp[(size_t)i * 20 + g];
    float a0 = di * (float)sv.x, a1 = di * (float)sv.y;
    int cnt = min(g_fill[i], ELL_CAP);
    const ull* ep = (const ull*)(g_ell + (size_t)i * ELL_CAP);
    int k = 0;
    for (; k + 8 <= cnt; k += 8) {
        ull raw[8];
        #pragma unroll
        for (int j = 0; j < 8; ++j) raw[j] = ep[k + j];
        float dc[8];
        #pragma unroll
        for (int j = 0; j < 8; ++j) dc[j] = g_dinv[(unsigned)(raw[j] & 0xffffffffu)];
        half2v v[8];
        #pragma unroll
        for (int j = 0; j < 8; ++j)
            v[j] = hp[(size_t)(unsigned)(raw[j] & 0xffffffffu) * 20 + g];
        #pragma unroll
        for (int j = 0; j < 8; ++j) {
            float nv = __int_as_float((int)(raw[j] >> 32)) * dc[j];
            a0 += nv * (float)v[j].x; a1 += nv * (float)v[j].y;
        }
    }
    for (; k < cnt; ++k) {
        ull raw = ep[k];
        unsigned c = (unsigned)(raw & 0xffffffffu);
        float nv = __int_as_float((int)(raw >> 32)) * g_dinv[c];
        half2v v = hp[(size_t)c * 20 + g];
        a0 += nv * (float)v.x; a1 += nv * (float)v.y;
    }
    float2 b = ((const float2*)bias)[g];
    ((float2*)(out + (size_t)i * OUT_C))[g] = make_float2(di * a0 + b.x, di * a1 + b.y);
}

// ---------------- fused co-launch kernels (sequential ranges, r5-proven) ----
// F0: gemm layer-0 || ELL fill (4/thread) || label convert (half4)
__global__ __launch_bounds__(256) void fused0(const float* __restrict__ x,
                                              const int* __restrict__ ei,
                                              const float* __restrict__ ew,
                                              const float* __restrict__ lab1,
                                              const float* __restrict__ lab2) {
    int b = blockIdx.x;
    if (b < GT64)             gemm_body<IN_C, float>(x, g_w0t, g_Ah, N_NODES, b);
    else if (b < GT64 + FB4)  fill4_body(ei, ei + N_EDGES, ew, b - GT64);
    else                      cvt4_body(lab1, lab2, g_l80a, b - GT64 - FB4);
}

// P1: GCN prop layer-0 || LPA pass 1 (even/odd, r5-proven)
__global__ __launch_bounds__(256) void fused_p1(const float* __restrict__ b0) {
    int b = blockIdx.x;
    if ((b & 1) == 0) prop256_body(g_Ah, g_P, b0, b >> 1);
    else              prop80_body<false>(g_l80a, g_l80b, nullptr, nullptr, b >> 1);
}

// G1: gemm layer-1 || LPA pass 2 (sequential ranges, r5-proven)
__global__ __launch_bounds__(256) void fused_g1() {
    int b = blockIdx.x;
    if (b < GT64) gemm_body<HID_C, _Float16>(g_h16, g_w1t, g_Ah, N_NODES, b);
    else          prop80_body<false>(g_l80b, g_l80a, nullptr, nullptr, b - GT64);
}

// prop256 layer-1 standalone (LPA3 moved to tail co-launch)
__global__ __launch_bounds__(256) void prop256_k(const float* __restrict__ b1) {
    prop256_body(g_Ah, g_P, b1, blockIdx.x);
}

// tail: GCN output prop || LPA pass 3 (final). 1:2 block ratio (bijective).
__global__ __launch_bounds__(256) void fused_tail(const float* __restrict__ b2,
                                                  float* __restrict__ out,
                                                  float* __restrict__ o1,
                                                  float* __restrict__ o2) {
    int b = blockIdx.x;
    int q = b / 3, r = b - q * 3;
    if (r == 0) prop40_body(g_o40h, out, b2, q);
    else        prop80_body<true>(g_l80a, nullptr, o1, o2, 2 * q + (r - 1));
}

// ---------------- graph small kernels ----------------
__global__ __launch_bounds__(256) void deg_dinv() {
    int i = blockIdx.x * blockDim.x + threadIdx.x;
    if (i >= N_NODES) return;
    int cnt = min(g_fill[i], ELL_CAP);
    const int2* ep = g_ell + (size_t)i * ELL_CAP;
    float s = 0.f;
    for (int p = 0; p < cnt; ++p) s += __int_as_float(ep[p].y);
    float d = s + 1.0f;   // + self-loop weight 1
    g_dinv[i] = (d > 0.f) ? rsqrtf(fmaxf(d, 1e-12f)) : 0.f;
}

// ---------------- conversions ----------------
__global__ void wtrans_blk(const float* __restrict__ W, _Float16* __restrict__ dst, int K) {
    int idx = blockIdx.x * blockDim.x + threadIdx.x;
    if (idx >= K * 256) return;
    int k = idx >> 8, n = idx & 255;
    int t = k >> 5, kl = k & 31, g = kl >> 3, j = kl & 7;
    dst[t * 8192 + n * 32 + ((g ^ (n & 3)) << 3) + j] = (_Float16)W[(size_t)k * 256 + n];
}

__global__ void wtrans_out(const float* __restrict__ W, _Float16* __restrict__ dst) {
    int idx = blockIdx.x * blockDim.x + threadIdx.x;
    if (idx >= 256 * 64) return;
    int k = idx >> 6, n = idx & 63;
    int g = k >> 3, j = k & 7;
    float v = (n < OUT_C) ? W[(size_t)k * OUT_C + n] : 0.f;
    dst[n * 256 + ((g ^ (n & 7)) << 3) + j] = (_Float16)v;
}

// BN scale/shift + ReLU on fp16: g_P -> g_h16
__global__ __launch_bounds__(256) void bn_apply16(const _Float16* __restrict__ h,
                                                  _Float16* __restrict__ out,
                                                  const float* __restrict__ scale,
                                                  const float* __restrict__ shift) {
    int i = blockIdx.x * blockDim.x + threadIdx.x;   // half4-group index
    if (i >= N_NODES * (HID_C / 4)) return;
    int c = (i & 63) * 4;
    half4v v = ((const half4v*)h)[i];
    half4v o;
    o.x = (_Float16)fmaxf((float)v.x * scale[c + 0] + shift[c + 0], 0.f);
    o.y = (_Float16)fmaxf((float)v.y * scale[c + 1] + shift[c + 1], 0.f);
    o.z = (_Float16)fmaxf((float)v.z * scale[c + 2] + shift[c + 2], 0.f);
    o.w = (_Float16)fmaxf((float)v.w * scale[c + 3] + shift[c + 3], 0.f);
    ((half4v*)out)[i] = o;
}

// Out layer: BM=128 (wave w -> 32 rows), N=40 (padded 64). Whole 32KB B panel
// staged to LDS once, A staged per-BK=32 step.
__global__ __launch_bounds__(256) void gemm_out_t(const _Float16* __restrict__ A,
                                                  const _Float16* __restrict__ Bblk,
                                                  _Float16* __restrict__ C, int M) {
    __shared__ _Float16 sB[64 * 256];   // 32KB, swizzled
    __shared__ _Float16 sA[128 * 40];   // 10KB
    const int K = HID_C;
    int t = threadIdx.x, lane = t & 63, w = t >> 6;
    int l31 = lane & 31, hi = lane >> 5;
    int m0 = blockIdx.x * 128;
    {   // stage whole B once (async)
        const _Float16* gp = Bblk + w * 4096 + lane * 8;
        _Float16* lp = &sB[w * 4096];
        #pragma unroll
        for (int i = 0; i < 8; ++i)
            gload_lds16(gp + i * 512, lp + i * 512);
    }
    f32x16 acc[2];
    #pragma unroll
    for (int nf = 0; nf < 2; ++nf)
        #pragma unroll
        for (int s = 0; s < 16; ++s) acc[nf][s] = 0.f;

    for (int k0 = 0; k0 < K; k0 += 32) {
        #pragma unroll
        for (int u = 0; u < 2; ++u) {
            int uu = t + u * 256;
            int r = uu >> 2, sg = uu & 3;
            int arow = min(m0 + r, M - 1);
            half8 av = *(const half8*)(A + (size_t)arow * K + k0 + sg * 8);
            *(half8*)&sA[r * 40 + sg * 8] = av;
        }
        __syncthreads();
        #pragma unroll
        for (int kk = 0; kk < 2; ++kk) {
            int gloc = kk * 2 + hi;
            int g = (k0 >> 3) + gloc;
            half8 af = *(const half8*)&sA[(w * 32 + l31) * 40 + gloc * 8];
            #pragma unroll
            for (int nf = 0; nf < 2; ++nf) {
                int n = nf * 32 + l31;
                half8 bf = *(const half8*)&sB[n * 256 + ((g ^ (n & 7)) << 3)];
                acc[nf] = __builtin_amdgcn_mfma_f32_32x32x16_f16(af, bf, acc[nf], 0, 0, 0);
            }
        }
        __syncthreads();
    }
    int mbase = m0 + w * 32 + 4 * hi;
    #pragma unroll
    for (int nf = 0; nf < 2; ++nf) {
        int n = nf * 32 + l31;
        if (n < OUT_C) {
            #pragma unroll
            for (int rr = 0; rr < 16; ++rr) {
                int m = mbase + (rr & 3) + 8 * (rr >> 2);
                if (m < M) C[(size_t)m * OUT_C + n] = (_Float16)acc[nf][rr];
            }
        }
    }
}

// ---------------- batchnorm stats (fp16 input, 32 rows/block) ----------------
__global__ __launch_bounds__(256) void bn_stats16(const _Float16* __restrict__ h, int layer) {
    int c = threadIdx.x;
    int r0 = blockIdx.x * 32;
    int rend = min(r0 + 32, N_NODES);
    float s = 0.f, ss = 0.f;
    for (int i = r0; i < rend; ++i) {
        float v = (float)h[(size_t)i * HID_C + c];
        s += v; ss += v * v;
    }
    atomicAdd(&g_bnstat[layer * 512 + c], s);
    atomicAdd(&g_bnstat[layer * 512 + 256 + c], ss);
}

__global__ void bn_final(int layer, const float* __restrict__ gamma,
                         const float* __restrict__ beta) {
    int c = threadIdx.x;
    float sum = g_bnstat[layer * 512 + c];
    float ss  = g_bnstat[layer * 512 + 256 + c];
    float mu  = sum / (float)N_NODES;
    float var = fmaxf(ss / (float)N_NODES - mu * mu, 0.f);
    float scale = gamma[c] * rsqrtf(var + BN_EPS);
    g_bnss[layer * 512 + c]       = scale;
    g_bnss[layer * 512 + 256 + c] = beta[c] - mu * scale;
}

// ---------------- host ----------------
template <typename T>
static T* symaddr(const void* sym) {
    void* p = nullptr;
    (void)hipGetSymbolAddress(&p, sym);
    return (T*)p;
}

extern "C" void kernel_launch(void* const* d_in, const int* in_sizes, int n_in,
                              void* d_out, int out_size, void* d_ws, size_t ws_size,
                              hipStream_t stream) {
    const float* x    = (const float*)d_in[0];
    const int*   ei   = (const int*)d_in[1];
    const float* lab1 = (const float*)d_in[2];
    const float* lab2 = (const float*)d_in[3];
    const float* ew   = (const float*)d_in[4];
    const float* W0   = (const float*)d_in[5];
    const float* b0   = (const float*)d_in[6];
    const float* W1   = (const float*)d_in[7];
    const float* b1   = (const float*)d_in[8];
    const float* W2   = (const float*)d_in[9];
    const float* b2   = (const float*)d_in[10];
    const float* gg0  = (const float*)d_in[11];
    const float* be0  = (const float*)d_in[12];
    const float* gg1  = (const float*)d_in[13];
    const float* be1  = (const float*)d_in[14];

    _Float16* ph16 = symaddr<_Float16>(HIP_SYMBOL(g_h16));
    _Float16* pP   = symaddr<_Float16>(HIP_SYMBOL(g_P));
    _Float16* po40 = symaddr<_Float16>(HIP_SYMBOL(g_o40h));
    _Float16* pw0t = symaddr<_Float16>(HIP_SYMBOL(g_w0t));
    _Float16* pw1t = symaddr<_Float16>(HIP_SYMBOL(g_w1t));
    _Float16* pw2t = symaddr<_Float16>(HIP_SYMBOL(g_w2t));
    int*   pfil = symaddr<int>(HIP_SYMBOL(g_fill));
    float* pbst = symaddr<float>(HIP_SYMBOL(g_bnstat));
    float* pbss = symaddr<float>(HIP_SYMBOL(g_bnss));

    hipMemsetAsync(pfil, 0, N_NODES * sizeof(int),   stream);
    hipMemsetAsync(pbst, 0, 4 * HID_C * sizeof(float), stream);

    // weight transposes (blocked+swizzled); W0 must precede fused0's gemm
    wtrans_blk<<<(IN_C * 256 + 255) / 256, 256, 0, stream>>>(W0, pw0t, IN_C);
    wtrans_blk<<<(HID_C * 256 + 255) / 256, 256, 0, stream>>>(W1, pw1t, HID_C);
    wtrans_out<<<(256 * 64 + 255) / 256, 256, 0, stream>>>(W2, pw2t);

    const int GB32 = (N_NODES + 31) / 32;    // 1563
    const int CB   = (N_NODES * 64 + 255) / 256;
    float* outf = (float*)d_out;    // fp32: out | y_hat | y_hat2

    // F0: gemm layer-0 || ELL fill || label convert (sequential ranges)
    fused0<<<GT64 + FB4 + CVT4, 256, 0, stream>>>(x, ei, ew, lab1, lab2);
    deg_dinv<<<(N_NODES + 255) / 256, 256, 0, stream>>>();

    // P1: prop layer-0 || LPA pass 1 (even/odd)
    fused_p1<<<PB + PB, 256, 0, stream>>>(b0);
    bn_stats16<<<GB32, 256, 0, stream>>>(pP, 0);
    bn_final<<<1, 256, 0, stream>>>(0, gg0, be0);
    bn_apply16<<<CB, 256, 0, stream>>>(pP, ph16, pbss, pbss + 256);

    // G1: gemm layer-1 || LPA pass 2 (sequential ranges)
    fused_g1<<<GT64 + PB, 256, 0, stream>>>();

    // prop layer-1 (standalone; LPA3 moved to tail)
    prop256_k<<<PB, 256, 0, stream>>>(b1);
    bn_stats16<<<GB32, 256, 0, stream>>>(pP, 1);
    bn_final<<<1, 256, 0, stream>>>(1, gg1, be1);
    bn_apply16<<<CB, 256, 0, stream>>>(pP, ph16, pbss + 512, pbss + 768);

    // layer 2 gemm, then tail: GCN output prop || LPA pass 3
    gemm_out_t<<<(N_NODES + 127) / 128, 256, 0, stream>>>(ph16, pw2t, po40, N_NODES);
    fused_tail<<<(N_NODES / 8) * 3, 256, 0, stream>>>(b2, outf,
                                                      outf + (size_t)N_NODES * OUT_C,
                                                      outf + 2 * (size_t)N_NODES * OUT_C);
}